// Round 7
// baseline (520.149 us; speedup 1.0000x reference)
//
#include <hip/hip_runtime.h>
#include <stdint.h>

#define DEV __device__ __forceinline__

// ---------- problem constants ----------
#define BP 96
#define NTOK 196
#define DIM 512
#define HID 256
#define NS 500
#define TOPK 49
#define ROWS (BP * NTOK)          // 18816
#define RB 32                     // rows per GEMM block
#define BK 16                     // k-tile
#define NB (DIM / BK)             // 32 chunks, GEMM1
#define NC (HID / BK)             // 16 chunks, GEMM2

// ---------- math helpers ----------
DEV float gelu32(float v) {
  return 0.5f * v * (1.0f + erff(v * 0.70710678f));
}

// async global->LDS, 16B per lane, wave-uniform LDS base (HW adds lane*16)
DEV void gld_lds16(const float* g, float* l) {
  __builtin_amdgcn_global_load_lds(
      (const __attribute__((address_space(1))) void*)g,
      (__attribute__((address_space(3))) void*)l, 16, 0, 0);
}

// Threefry-2x32, 20 rounds, key = (0, 1)  (jax.random.key(1))
DEV void threefry2x32(uint32_t x0, uint32_t x1, uint32_t& o0, uint32_t& o1) {
  const uint32_t k0 = 0u, k1 = 1u;
  const uint32_t k2 = 0x1BD11BDAu ^ k0 ^ k1;
  x0 += k0; x1 += k1;
#define TF_R(r) { x0 += x1; x1 = (x1 << (r)) | (x1 >> (32 - (r))); x1 ^= x0; }
  TF_R(13) TF_R(15) TF_R(26) TF_R(6)
  x0 += k1; x1 += k2 + 1u;
  TF_R(17) TF_R(29) TF_R(16) TF_R(24)
  x0 += k2; x1 += k0 + 2u;
  TF_R(13) TF_R(15) TF_R(26) TF_R(6)
  x0 += k0; x1 += k1 + 3u;
  TF_R(17) TF_R(29) TF_R(16) TF_R(24)
  x0 += k1; x1 += k2 + 4u;
  TF_R(13) TF_R(15) TF_R(26) TF_R(6)
  x0 += k2; x1 += k0 + 5u;
#undef TF_R
  o0 = x0; o1 = x1;
}

// XLA ErfInv32 (Giles polynomial)
DEV float erfinv_xla(float x) {
  float w = -log1pf(-x * x);
  float ws = w - 2.5f;
  float wl = sqrtf(w) - 3.0f;
  float ps = 2.81022636e-08f;
  ps = fmaf(ps, ws, 3.43273939e-07f);
  ps = fmaf(ps, ws, -3.5233877e-06f);
  ps = fmaf(ps, ws, -4.39150654e-06f);
  ps = fmaf(ps, ws, 0.00021858087f);
  ps = fmaf(ps, ws, -0.00125372503f);
  ps = fmaf(ps, ws, -0.00417768164f);
  ps = fmaf(ps, ws, 0.246640727f);
  ps = fmaf(ps, ws, 1.50140941f);
  float pl = -0.000200214257f;
  pl = fmaf(pl, wl, 0.000100950558f);
  pl = fmaf(pl, wl, 0.00134934322f);
  pl = fmaf(pl, wl, -0.00367342844f);
  pl = fmaf(pl, wl, 0.00573950773f);
  pl = fmaf(pl, wl, -0.0076224613f);
  pl = fmaf(pl, wl, 0.00943887047f);
  pl = fmaf(pl, wl, 1.00167406f);
  pl = fmaf(pl, wl, 2.83297682f);
  return (w < 5.0f ? ps : pl) * x;
}

// jax-f32-faithful N(0,1) noise, PARTITIONABLE threefry: counter=(0,g), draw=o0^o1
DEV float noise_at(unsigned g) {
  unsigned o0, o1;
  threefry2x32(0u, g, o0, o1);
  unsigned bits = o0 ^ o1;
  float f = __uint_as_float((bits >> 9) | 0x3f800000u) - 1.0f;
  float u = f * 2.0f - 0.99999994f;
  u = fmaxf(-0.99999994f, u);
  return 1.41421356f * erfinv_xla(u);
}

#define FMA_BLOCK(a4, b0, b1, e, dstLo, dstHi)                                 \
  {                                                                            \
    _Pragma("unroll")                                                          \
    for (int i = 0; i < 4; ++i) {                                              \
      float av = (e == 0) ? a4[i].x : (e == 1) ? a4[i].y                       \
                 : (e == 2) ? a4[i].z : a4[i].w;                               \
      dstLo[i][0] = fmaf(av, b0.x, dstLo[i][0]);                               \
      dstLo[i][1] = fmaf(av, b0.y, dstLo[i][1]);                               \
      dstLo[i][2] = fmaf(av, b0.z, dstLo[i][2]);                               \
      dstLo[i][3] = fmaf(av, b0.w, dstLo[i][3]);                               \
      dstHi[i][0] = fmaf(av, b1.x, dstHi[i][0]);                               \
      dstHi[i][1] = fmaf(av, b1.y, dstHi[i][1]);                               \
      dstHi[i][2] = fmaf(av, b1.z, dstHi[i][2]);                               \
      dstHi[i][3] = fmaf(av, b1.w, dstHi[i][3]);                               \
    }                                                                          \
  }

// ---------- K0: guidance constants c1,c2 (96 x 256 each, f32) ----------
__global__ __launch_bounds__(256) void k_glob(
    const float* __restrict__ gf, const float* __restrict__ gs,
    const float* __restrict__ lng, const float* __restrict__ lnb,
    const float* __restrict__ Wgd, const float* __restrict__ Wout1,
    float* __restrict__ cout) {
  int bq = blockIdx.x >> 1, which = blockIdx.x & 1;
  const float* row = which ? (gs + (size_t)(bq / 12) * DIM) : (gf + (size_t)bq * DIM);
  __shared__ float lx[DIM];
  __shared__ float sg[HID];
  __shared__ double sred[8];
  int tid = threadIdx.x, lane = tid & 63, wv = tid >> 6;
  float v0 = row[tid], v1 = row[tid + 256];
  double s = (double)v0 + v1, q = (double)v0 * v0 + (double)v1 * v1;
  #pragma unroll
  for (int m = 1; m < 64; m <<= 1) { s += __shfl_xor(s, m); q += __shfl_xor(q, m); }
  if (lane == 0) { sred[wv * 2] = s; sred[wv * 2 + 1] = q; }
  __syncthreads();
  double ts = sred[0] + sred[2] + sred[4] + sred[6];
  double tq = sred[1] + sred[3] + sred[5] + sred[7];
  double mean = ts / 512.0;
  double var = tq / 512.0 - mean * mean;
  float mn = (float)mean;
  float rs = (float)(1.0 / sqrt(var + 1e-5));
  lx[tid]       = (v0 - mn) * rs * lng[tid] + lnb[tid];
  lx[tid + 256] = (v1 - mn) * rs * lng[tid + 256] + lnb[tid + 256];
  __syncthreads();
  float acc = 0.0f;
  for (int d = 0; d < DIM; ++d) acc = fmaf(lx[d], Wgd[(size_t)d * HID + tid], acc);
  sg[tid] = gelu32(acc);
  __syncthreads();
  float c = 0.0f;
  for (int j = 0; j < HID; ++j) c = fmaf(sg[j], Wout1[(size_t)(HID + j) * HID + tid], c);
  cout[((size_t)which * BP + bq) * HID + tid] = c;
}

// ---------- K1: Wg = g*Win, gw = sum g*Win, bw = sum b*Win (1 block) ----------
__global__ __launch_bounds__(256) void k_wprep(
    const float* __restrict__ g, const float* __restrict__ b,
    const float* __restrict__ Win, float* __restrict__ Wg,
    float* __restrict__ gwv, float* __restrict__ bwv) {
  int j = threadIdx.x;
  float sg = 0.0f, sb = 0.0f;
  for (int d = 0; d < DIM; ++d) {
    float w = Win[(size_t)d * HID + j];
    float wg = w * g[d];
    Wg[(size_t)d * HID + j] = wg;
    sg += wg;                 // matches r4 accumulation order/ops
    sb = fmaf(b[d], w, sb);
  }
  gwv[j] = sg;
  bwv[j] = sb;
}

// ---------- K2: per-row mean/rstd of x (f64 stats, f32 out) ----------
__global__ __launch_bounds__(256) void k_stats(const float* __restrict__ x,
                                               float* __restrict__ stats) {
  int r = blockIdx.x * 4 + (threadIdx.x >> 6);
  int lane = threadIdx.x & 63;
  const float4* xr = (const float4*)(x + (size_t)r * DIM);
  float4 a = xr[lane], c = xr[lane + 64];
  double s = (double)a.x + a.y + a.z + a.w + (double)c.x + c.y + c.z + c.w;
  double q = (double)a.x * a.x + (double)a.y * a.y + (double)a.z * a.z + (double)a.w * a.w +
             (double)c.x * c.x + (double)c.y * c.y + (double)c.z * c.z + (double)c.w * c.w;
  #pragma unroll
  for (int m = 1; m < 64; m <<= 1) { s += __shfl_xor(s, m); q += __shfl_xor(q, m); }
  if (lane == 0) {
    double mean = s / 512.0;
    double var = q / 512.0 - mean * mean;
    stats[r * 2]     = (float)mean;
    stats[r * 2 + 1] = (float)(1.0 / sqrt(var + 1e-5));
  }
}

// ---------- K3: GEMM1  local = gelu(rs*(x@Wg) - rs*m*gw + bw) ----------
// 256 thr = 8 row-groups x 32 col-groups; thread tile 4 rows x (4+4) cols.
__global__ __launch_bounds__(256, 4) void k_gemm1(
    const float* __restrict__ x, const float* __restrict__ Wg,
    const float* __restrict__ stats, const float* __restrict__ gwv,
    const float* __restrict__ bwv, float* __restrict__ local_) {
  __shared__ float As[2][RB][BK];   // 4 KB
  __shared__ float Bs[2][BK][HID];  // 32 KB
  const int tid = threadIdx.x, lane = tid & 63, wv = tid >> 6;
  const int rg = tid >> 5, cg = tid & 31;
  const int r0 = rg * 4, cLo = cg * 4, cHi = cg * 4 + 128;
  const int gr0 = blockIdx.x * RB;

  auto stageA = [&](int kc, int pb) {
    if (wv < 2)
      gld_lds16(x + (size_t)(gr0 + wv * 16 + (lane >> 2)) * DIM + kc + (lane & 3) * 4,
                &As[pb][wv * 16][0]);
  };
  auto stageB = [&](int kc, int pb) {
    #pragma unroll
    for (int rr = 0; rr < 4; ++rr)
      gld_lds16(Wg + (size_t)(kc + wv * 4 + rr) * HID + lane * 4,
                &Bs[pb][wv * 4 + rr][0]);
  };

  float aLo[4][4] = {}, aHi[4][4] = {};
  stageA(0, 0); stageB(0, 0);
  __syncthreads();
  for (int t = 0; t < NB; ++t) {
    const int pb = t & 1;
    if (t + 1 < NB) { stageA((t + 1) * BK, pb ^ 1); stageB((t + 1) * BK, pb ^ 1); }
    #pragma unroll
    for (int k4 = 0; k4 < BK; k4 += 4) {
      float4 a4[4];
      #pragma unroll
      for (int i = 0; i < 4; ++i) a4[i] = *(const float4*)&As[pb][r0 + i][k4];
      #pragma unroll
      for (int e = 0; e < 4; ++e) {
        float4 b0 = *(const float4*)&Bs[pb][k4 + e][cLo];
        float4 b1 = *(const float4*)&Bs[pb][k4 + e][cHi];
        FMA_BLOCK(a4, b0, b1, e, aLo, aHi)
      }
    }
    __syncthreads();
  }

  float4 gwLo = *(const float4*)(gwv + cLo), gwHi = *(const float4*)(gwv + cHi);
  float4 bwLo = *(const float4*)(bwv + cLo), bwHi = *(const float4*)(bwv + cHi);
  #pragma unroll
  for (int i = 0; i < 4; ++i) {
    int row = gr0 + r0 + i;
    float mn = stats[row * 2], rs = stats[row * 2 + 1];
    float4 lo, hi;
    lo.x = gelu32(rs * aLo[i][0] - rs * mn * gwLo.x + bwLo.x);
    lo.y = gelu32(rs * aLo[i][1] - rs * mn * gwLo.y + bwLo.y);
    lo.z = gelu32(rs * aLo[i][2] - rs * mn * gwLo.z + bwLo.z);
    lo.w = gelu32(rs * aLo[i][3] - rs * mn * gwLo.w + bwLo.w);
    hi.x = gelu32(rs * aHi[i][0] - rs * mn * gwHi.x + bwHi.x);
    hi.y = gelu32(rs * aHi[i][1] - rs * mn * gwHi.y + bwHi.y);
    hi.z = gelu32(rs * aHi[i][2] - rs * mn * gwHi.z + bwHi.z);
    hi.w = gelu32(rs * aHi[i][3] - rs * mn * gwHi.w + bwHi.w);
    *(float4*)(local_ + (size_t)row * HID + cLo) = lo;
    *(float4*)(local_ + (size_t)row * HID + cHi) = hi;
  }
}

// ---------- K4: GEMM2  U = local@W1; scores = tanh(red(c1)) + tanh(red(c2)) ----------
__global__ __launch_bounds__(256, 4) void k_gemm2(
    const float* __restrict__ local_, const float* __restrict__ W1,
    const float* __restrict__ W2, const float* __restrict__ c1,
    const float* __restrict__ c2, float* __restrict__ scores) {
  __shared__ float As[2][RB][BK];   // 4 KB
  __shared__ float Bs[2][BK][HID];  // 32 KB
  const int tid = threadIdx.x, lane = tid & 63, wv = tid >> 6;
  const int rg = tid >> 5, cg = tid & 31;
  const int r0 = rg * 4, cLo = cg * 4, cHi = cg * 4 + 128;
  const int gr0 = blockIdx.x * RB;

  auto stageA = [&](int kc, int pb) {
    if (wv < 2)
      gld_lds16(local_ + (size_t)(gr0 + wv * 16 + (lane >> 2)) * HID + kc + (lane & 3) * 4,
                &As[pb][wv * 16][0]);
  };
  auto stageB = [&](int kc, int pb) {
    #pragma unroll
    for (int rr = 0; rr < 4; ++rr)
      gld_lds16(W1 + (size_t)(kc + wv * 4 + rr) * HID + lane * 4,
                &Bs[pb][wv * 4 + rr][0]);
  };

  float uLo[4][4] = {}, uHi[4][4] = {};
  stageA(0, 0); stageB(0, 0);
  __syncthreads();
  for (int t = 0; t < NC; ++t) {
    const int pb = t & 1;
    if (t + 1 < NC) { stageA((t + 1) * BK, pb ^ 1); stageB((t + 1) * BK, pb ^ 1); }
    #pragma unroll
    for (int k4 = 0; k4 < BK; k4 += 4) {
      float4 a4[4];
      #pragma unroll
      for (int i = 0; i < 4; ++i) a4[i] = *(const float4*)&As[pb][r0 + i][k4];
      #pragma unroll
      for (int e = 0; e < 4; ++e) {
        float4 b0 = *(const float4*)&Bs[pb][k4 + e][cLo];
        float4 b1 = *(const float4*)&Bs[pb][k4 + e][cHi];
        FMA_BLOCK(a4, b0, b1, e, uLo, uHi)
      }
    }
    __syncthreads();
  }

  float4 w2lo = *(const float4*)(W2 + cLo);
  float4 w2hi = *(const float4*)(W2 + cHi);
  #pragma unroll
  for (int i = 0; i < 4; ++i) {
    int row = gr0 + r0 + i;
    int bf = row / NTOK;
    const float* c1p = c1 + (size_t)bf * HID;
    const float* c2p = c2 + (size_t)bf * HID;
    float4 c1lo = *(const float4*)(c1p + cLo), c1hi = *(const float4*)(c1p + cHi);
    float4 c2lo = *(const float4*)(c2p + cLo), c2hi = *(const float4*)(c2p + cHi);
    float s1 = gelu32(uLo[i][0] + c1lo.x) * w2lo.x + gelu32(uLo[i][1] + c1lo.y) * w2lo.y +
               gelu32(uLo[i][2] + c1lo.z) * w2lo.z + gelu32(uLo[i][3] + c1lo.w) * w2lo.w +
               gelu32(uHi[i][0] + c1hi.x) * w2hi.x + gelu32(uHi[i][1] + c1hi.y) * w2hi.y +
               gelu32(uHi[i][2] + c1hi.z) * w2hi.z + gelu32(uHi[i][3] + c1hi.w) * w2hi.w;
    float s2 = gelu32(uLo[i][0] + c2lo.x) * w2lo.x + gelu32(uLo[i][1] + c2lo.y) * w2lo.y +
               gelu32(uLo[i][2] + c2lo.z) * w2lo.z + gelu32(uLo[i][3] + c2lo.w) * w2lo.w +
               gelu32(uHi[i][0] + c2hi.x) * w2hi.x + gelu32(uHi[i][1] + c2hi.y) * w2hi.y +
               gelu32(uHi[i][2] + c2hi.z) * w2hi.z + gelu32(uHi[i][3] + c2hi.w) * w2hi.w;
    #pragma unroll
    for (int m = 1; m < 32; m <<= 1) { s1 += __shfl_xor(s1, m); s2 += __shfl_xor(s2, m); }
    if (cg == 0) scores[row] = tanhf(s1) + tanhf(s2);
  }
}

// ---------- K5: perturbed top-k scatter, f32 keys, int counts ----------
__global__ __launch_bounds__(256) void k_topk(const float* __restrict__ scores,
                                              int* __restrict__ cnt) {
  int sid = blockIdx.x * 4 + (threadIdx.x >> 6);  // 0..47999
  int lane = threadIdx.x & 63;
  int b = sid / NS;
  unsigned key[4];
  #pragma unroll
  for (int c = 0; c < 4; ++c) {
    int j = c * 64 + lane;
    if (j < NTOK) {
      float n = noise_at((unsigned)sid * 196u + (unsigned)j);
      float p = fmaf(0.05f, n, scores[b * NTOK + j]);
      unsigned ub = __float_as_uint(p);
      key[c] = (ub & 0x80000000u) ? ~ub : (ub | 0x80000000u);
    } else {
      key[c] = 0u;
    }
  }
  unsigned prefix = 0u;
  for (int bit = 31; bit >= 0; --bit) {
    unsigned t = prefix | (1u << bit);
    int cn = 0;
    #pragma unroll
    for (int c = 0; c < 4; ++c) cn += __popcll(__ballot(key[c] >= t));
    if (cn >= TOPK) prefix = t;
  }
  unsigned long long mE[4];
  int cntG = 0;
  #pragma unroll
  for (int c = 0; c < 4; ++c) {
    cntG += __popcll(__ballot(key[c] > prefix));
    mE[c] = __ballot(key[c] == prefix);
  }
  int need = TOPK - cntG;
  unsigned long long lt = (1ull << lane) - 1ull;
  bool sel[4];
  #pragma unroll
  for (int c = 0; c < 4; ++c) {
    int er = 0;
    for (int cc = 0; cc < c; ++cc) er += __popcll(mE[cc]);
    er += __popcll(mE[c] & lt);
    sel[c] = (key[c] > prefix) || ((key[c] == prefix) && (er < need));
  }
  unsigned long long mS[4];
  #pragma unroll
  for (int c = 0; c < 4; ++c) mS[c] = __ballot(sel[c]);
  int base = 0;
  #pragma unroll
  for (int c = 0; c < 4; ++c) {
    if (sel[c]) {
      int rank = base + __popcll(mS[c] & lt);
      int j = c * 64 + lane;
      atomicAdd(&cnt[((size_t)b * TOPK + rank) * NTOK + j], 1);
    }
    base += __popcll(mS[c]);
  }
}

// ---------- K6: out[b,k,:] = sum_l (cnt/500) * x[b,l,:] ----------
__global__ __launch_bounds__(128) void k_out(const float* __restrict__ x,
                                             const int* __restrict__ cnt,
                                             float* __restrict__ out) {
  int bk = blockIdx.x;
  int b = bk / TOPK;
  __shared__ float sw[NTOK];
  for (int l = threadIdx.x; l < NTOK; l += 128)
    sw[l] = (float)cnt[(size_t)bk * NTOK + l] * 0.002f;
  __syncthreads();
  int d = threadIdx.x * 4;
  float a0 = 0, a1 = 0, a2 = 0, a3 = 0;
  for (int l = 0; l < NTOK; ++l) {
    float w = sw[l];
    if (w != 0.0f) {
      float4 xv = *(const float4*)(x + ((size_t)(b * NTOK + l)) * DIM + d);
      a0 = fmaf(w, xv.x, a0); a1 = fmaf(w, xv.y, a1);
      a2 = fmaf(w, xv.z, a2); a3 = fmaf(w, xv.w, a3);
    }
  }
  float4 o = {a0, a1, a2, a3};
  *(float4*)(out + (size_t)bk * DIM + d) = o;
}

// ---------- launcher ----------
extern "C" void kernel_launch(void* const* d_in, const int* in_sizes, int n_in,
                              void* d_out, int out_size, void* d_ws, size_t ws_size,
                              hipStream_t stream) {
  const float* x       = (const float*)d_in[0];
  const float* gf      = (const float*)d_in[1];
  const float* gs      = (const float*)d_in[2];
  const float* ln_in_g = (const float*)d_in[3];
  const float* ln_in_b = (const float*)d_in[4];
  const float* W_in    = (const float*)d_in[5];
  const float* ln_gd_g = (const float*)d_in[6];
  const float* ln_gd_b = (const float*)d_in[7];
  const float* W_gd    = (const float*)d_in[8];
  const float* W_out1  = (const float*)d_in[9];
  const float* W_out2  = (const float*)d_in[10];
  float* out = (float*)d_out;
  float* ws  = (float*)d_ws;

  // ws layout (floats): Wg | gw | bw | stats | c1 | c2 | scores | local | cnt  (~24 MB)
  float* Wg     = ws;                                  // 512*256
  float* gwv    = Wg + (size_t)DIM * HID;              // 256
  float* bwv    = gwv + HID;                           // 256
  float* stats  = bwv + HID;                           // 18816*2
  float* c1     = stats + (size_t)ROWS * 2;            // 96*256
  float* c2     = c1 + (size_t)BP * HID;               // 96*256
  float* scores = c2 + (size_t)BP * HID;               // 18816
  float* local_ = scores + ROWS;                       // 18816*256
  int*   cnt    = (int*)(local_ + (size_t)ROWS * HID); // 96*49*196

  hipMemsetAsync(cnt, 0, (size_t)BP * TOPK * NTOK * sizeof(int), stream);
  k_wprep<<<1, 256, 0, stream>>>(ln_in_g, ln_in_b, W_in, Wg, gwv, bwv);
  k_glob<<<192, 256, 0, stream>>>(gf, gs, ln_gd_g, ln_gd_b, W_gd, W_out1, c1);
  k_stats<<<ROWS / 4, 256, 0, stream>>>(x, stats);
  k_gemm1<<<ROWS / RB, 256, 0, stream>>>(x, Wg, stats, gwv, bwv, local_);
  k_gemm2<<<ROWS / RB, 256, 0, stream>>>(local_, W_out1, W_out2, c1, c2, scores);
  k_topk<<<(BP * NS) / 4, 256, 0, stream>>>(scores, cnt);
  k_out<<<BP * TOPK, 128, 0, stream>>>(x, cnt, out);
}

// Round 8
// 356.567 us; speedup vs baseline: 1.4588x; 1.4588x over previous
//
#include <hip/hip_runtime.h>
#include <stdint.h>

#define DEV __device__ __forceinline__

// ---------- problem constants ----------
#define BP 96
#define NTOK 196
#define DIM 512
#define HID 256
#define NS 500
#define TOPK 49
#define ROWS (BP * NTOK)          // 18816
#define GBLK (ROWS / 64)          // 294 blocks for MFMA GEMMs

typedef _Float16 f16x8 __attribute__((ext_vector_type(8)));
typedef float f32x4 __attribute__((ext_vector_type(4)));

// ---------- math helpers ----------
DEV float gelu32(float v) {
  return 0.5f * v * (1.0f + erff(v * 0.70710678f));
}

DEV void split8(const float* v, f16x8& h, f16x8& l) {
  #pragma unroll
  for (int e = 0; e < 8; ++e) {
    _Float16 hh = (_Float16)v[e];
    h[e] = hh;
    l[e] = (_Float16)(v[e] - (float)hh);
  }
}

// Threefry-2x32, 20 rounds, key = (0, 1)  (jax.random.key(1))
DEV void threefry2x32(uint32_t x0, uint32_t x1, uint32_t& o0, uint32_t& o1) {
  const uint32_t k0 = 0u, k1 = 1u;
  const uint32_t k2 = 0x1BD11BDAu ^ k0 ^ k1;
  x0 += k0; x1 += k1;
#define TF_R(r) { x0 += x1; x1 = (x1 << (r)) | (x1 >> (32 - (r))); x1 ^= x0; }
  TF_R(13) TF_R(15) TF_R(26) TF_R(6)
  x0 += k1; x1 += k2 + 1u;
  TF_R(17) TF_R(29) TF_R(16) TF_R(24)
  x0 += k2; x1 += k0 + 2u;
  TF_R(13) TF_R(15) TF_R(26) TF_R(6)
  x0 += k0; x1 += k1 + 3u;
  TF_R(17) TF_R(29) TF_R(16) TF_R(24)
  x0 += k1; x1 += k2 + 4u;
  TF_R(13) TF_R(15) TF_R(26) TF_R(6)
  x0 += k2; x1 += k0 + 5u;
#undef TF_R
  o0 = x0; o1 = x1;
}

// XLA ErfInv32 (Giles polynomial)
DEV float erfinv_xla(float x) {
  float w = -log1pf(-x * x);
  float ws = w - 2.5f;
  float wl = sqrtf(w) - 3.0f;
  float ps = 2.81022636e-08f;
  ps = fmaf(ps, ws, 3.43273939e-07f);
  ps = fmaf(ps, ws, -3.5233877e-06f);
  ps = fmaf(ps, ws, -4.39150654e-06f);
  ps = fmaf(ps, ws, 0.00021858087f);
  ps = fmaf(ps, ws, -0.00125372503f);
  ps = fmaf(ps, ws, -0.00417768164f);
  ps = fmaf(ps, ws, 0.246640727f);
  ps = fmaf(ps, ws, 1.50140941f);
  float pl = -0.000200214257f;
  pl = fmaf(pl, wl, 0.000100950558f);
  pl = fmaf(pl, wl, 0.00134934322f);
  pl = fmaf(pl, wl, -0.00367342844f);
  pl = fmaf(pl, wl, 0.00573950773f);
  pl = fmaf(pl, wl, -0.0076224613f);
  pl = fmaf(pl, wl, 0.00943887047f);
  pl = fmaf(pl, wl, 1.00167406f);
  pl = fmaf(pl, wl, 2.83297682f);
  return (w < 5.0f ? ps : pl) * x;
}

// jax-f32-faithful N(0,1) noise, PARTITIONABLE threefry: counter=(0,g), draw=o0^o1
DEV float noise_at(unsigned g) {
  unsigned o0, o1;
  threefry2x32(0u, g, o0, o1);
  unsigned bits = o0 ^ o1;
  float f = __uint_as_float((bits >> 9) | 0x3f800000u) - 1.0f;
  float u = f * 2.0f - 0.99999994f;
  u = fmaxf(-0.99999994f, u);
  return 1.41421356f * erfinv_xla(u);
}

// ---------- K0: guidance constants c1,c2 (96 x 256 each, f32) ----------
__global__ __launch_bounds__(256) void k_glob(
    const float* __restrict__ gf, const float* __restrict__ gs,
    const float* __restrict__ lng, const float* __restrict__ lnb,
    const float* __restrict__ Wgd, const float* __restrict__ Wout1,
    float* __restrict__ cout) {
  int bq = blockIdx.x >> 1, which = blockIdx.x & 1;
  const float* row = which ? (gs + (size_t)(bq / 12) * DIM) : (gf + (size_t)bq * DIM);
  __shared__ float lx[DIM];
  __shared__ float sg[HID];
  __shared__ double sred[8];
  int tid = threadIdx.x, lane = tid & 63, wv = tid >> 6;
  float v0 = row[tid], v1 = row[tid + 256];
  double s = (double)v0 + v1, q = (double)v0 * v0 + (double)v1 * v1;
  #pragma unroll
  for (int m = 1; m < 64; m <<= 1) { s += __shfl_xor(s, m); q += __shfl_xor(q, m); }
  if (lane == 0) { sred[wv * 2] = s; sred[wv * 2 + 1] = q; }
  __syncthreads();
  double ts = sred[0] + sred[2] + sred[4] + sred[6];
  double tq = sred[1] + sred[3] + sred[5] + sred[7];
  double mean = ts / 512.0;
  double var = tq / 512.0 - mean * mean;
  float mn = (float)mean;
  float rs = (float)(1.0 / sqrt(var + 1e-5));
  lx[tid]       = (v0 - mn) * rs * lng[tid] + lnb[tid];
  lx[tid + 256] = (v1 - mn) * rs * lng[tid + 256] + lnb[tid + 256];
  __syncthreads();
  float acc = 0.0f;
  for (int d = 0; d < DIM; ++d) acc = fmaf(lx[d], Wgd[(size_t)d * HID + tid], acc);
  sg[tid] = gelu32(acc);
  __syncthreads();
  float c = 0.0f;
  for (int j = 0; j < HID; ++j) c = fmaf(sg[j], Wout1[(size_t)(HID + j) * HID + tid], c);
  cout[((size_t)which * BP + bq) * HID + tid] = c;
}

// ---------- K1: transpose+split weights: WhT/WlT [256][512], W1hT/W1lT [256][256] ----------
__global__ __launch_bounds__(256) void k_prep(
    const float* __restrict__ Win, const float* __restrict__ W1,
    _Float16* __restrict__ WhT, _Float16* __restrict__ WlT,
    _Float16* __restrict__ W1hT, _Float16* __restrict__ W1lT) {
  int n = blockIdx.x;
  if (blockIdx.y == 0) {
    for (int k = threadIdx.x; k < DIM; k += 256) {
      float v = Win[(size_t)k * HID + n];
      _Float16 h = (_Float16)v;
      WhT[(size_t)n * DIM + k] = h;
      WlT[(size_t)n * DIM + k] = (_Float16)(v - (float)h);
    }
  } else {
    int k = threadIdx.x;
    float v = W1[(size_t)k * HID + n];
    _Float16 h = (_Float16)v;
    W1hT[(size_t)n * HID + k] = h;
    W1lT[(size_t)n * HID + k] = (_Float16)(v - (float)h);
  }
}

// ---------- K2: per-row mean/rstd of x (f64 stats, f32 out) ----------
__global__ __launch_bounds__(256) void k_stats(const float* __restrict__ x,
                                               float* __restrict__ stats) {
  int r = blockIdx.x * 4 + (threadIdx.x >> 6);
  int lane = threadIdx.x & 63;
  const float4* xr = (const float4*)(x + (size_t)r * DIM);
  float4 a = xr[lane], c = xr[lane + 64];
  double s = (double)a.x + a.y + a.z + a.w + (double)c.x + c.y + c.z + c.w;
  double q = (double)a.x * a.x + (double)a.y * a.y + (double)a.z * a.z + (double)a.w * a.w +
             (double)c.x * c.x + (double)c.y * c.y + (double)c.z * c.z + (double)c.w * c.w;
  #pragma unroll
  for (int m = 1; m < 64; m <<= 1) { s += __shfl_xor(s, m); q += __shfl_xor(q, m); }
  if (lane == 0) {
    double mean = s / 512.0;
    double var = q / 512.0 - mean * mean;
    stats[r * 2]     = (float)mean;
    stats[r * 2 + 1] = (float)(1.0 / sqrt(var + 1e-5));
  }
}

// ---------- K3: MFMA GEMM1  local = gelu(LN(x)g+b @ Win)  [fp16 split x3] ----------
// block: 64 rows x 256 cols, 4 waves (one 64-col group each), BK=32, 16 chunks.
__global__ __launch_bounds__(256, 2) void k_g1(
    const float* __restrict__ x, const float* __restrict__ stats,
    const float* __restrict__ g_in, const float* __restrict__ b_in,
    const _Float16* __restrict__ WhT, const _Float16* __restrict__ WlT,
    float* __restrict__ local_) {
  __shared__ _Float16 Ah[4][64][8], Al[4][64][8];     // 4KB + 4KB
  __shared__ _Float16 Bh[4][256][8], Bl[4][256][8];   // 16KB + 16KB
  const int tid = threadIdx.x, lane = tid & 63, w = tid >> 6;
  const int kg = lane >> 4, lr = lane & 15;
  const int gr0 = blockIdx.x * 64;
  const int arow = tid & 63, ag = tid >> 6;
  const float mn = stats[(gr0 + arow) * 2], rs = stats[(gr0 + arow) * 2 + 1];

  f32x4 acc[4][4];
  const f32x4 z4 = {0.f, 0.f, 0.f, 0.f};
  #pragma unroll
  for (int mi = 0; mi < 4; ++mi)
    #pragma unroll
    for (int ni = 0; ni < 4; ++ni) acc[mi][ni] = z4;

  for (int t = 0; t < 16; ++t) {
    const int kc = t * 32;
    // global loads for this chunk (issue before barrier)
    float xv[8], gv[8], bv[8];
    *(float4*)&xv[0] = *(const float4*)&x[(size_t)(gr0 + arow) * DIM + kc + ag * 8];
    *(float4*)&xv[4] = *(const float4*)&x[(size_t)(gr0 + arow) * DIM + kc + ag * 8 + 4];
    *(float4*)&gv[0] = *(const float4*)&g_in[kc + ag * 8];
    *(float4*)&gv[4] = *(const float4*)&g_in[kc + ag * 8 + 4];
    *(float4*)&bv[0] = *(const float4*)&b_in[kc + ag * 8];
    *(float4*)&bv[4] = *(const float4*)&b_in[kc + ag * 8 + 4];
    f16x8 wbh[4], wbl[4];
    #pragma unroll
    for (int gg = 0; gg < 4; ++gg) {
      wbh[gg] = *(const f16x8*)&WhT[(size_t)tid * DIM + kc + gg * 8];
      wbl[gg] = *(const f16x8*)&WlT[(size_t)tid * DIM + kc + gg * 8];
    }
    float xnv[8];
    #pragma unroll
    for (int e = 0; e < 8; ++e) xnv[e] = fmaf((xv[e] - mn) * rs, gv[e], bv[e]);
    f16x8 ha, la;
    split8(xnv, ha, la);

    __syncthreads();   // previous chunk's frag reads complete
    *(f16x8*)&Ah[ag][arow][0] = ha;
    *(f16x8*)&Al[ag][arow][0] = la;
    #pragma unroll
    for (int gg = 0; gg < 4; ++gg) {
      *(f16x8*)&Bh[gg][tid][0] = wbh[gg];
      *(f16x8*)&Bl[gg][tid][0] = wbl[gg];
    }
    __syncthreads();

    f16x8 fah[4], fal[4], fbh[4], fbl[4];
    #pragma unroll
    for (int mi = 0; mi < 4; ++mi) {
      fah[mi] = *(const f16x8*)&Ah[kg][mi * 16 + lr][0];
      fal[mi] = *(const f16x8*)&Al[kg][mi * 16 + lr][0];
    }
    #pragma unroll
    for (int ni = 0; ni < 4; ++ni) {
      fbh[ni] = *(const f16x8*)&Bh[kg][w * 64 + ni * 16 + lr][0];
      fbl[ni] = *(const f16x8*)&Bl[kg][w * 64 + ni * 16 + lr][0];
    }
    #pragma unroll
    for (int mi = 0; mi < 4; ++mi)
      #pragma unroll
      for (int ni = 0; ni < 4; ++ni) {
        acc[mi][ni] = __builtin_amdgcn_mfma_f32_16x16x32_f16(fah[mi], fbh[ni], acc[mi][ni], 0, 0, 0);
        acc[mi][ni] = __builtin_amdgcn_mfma_f32_16x16x32_f16(fah[mi], fbl[ni], acc[mi][ni], 0, 0, 0);
        acc[mi][ni] = __builtin_amdgcn_mfma_f32_16x16x32_f16(fal[mi], fbh[ni], acc[mi][ni], 0, 0, 0);
      }
  }

  // epilogue: gelu -> local (f32)
  #pragma unroll
  for (int mi = 0; mi < 4; ++mi)
    #pragma unroll
    for (int ni = 0; ni < 4; ++ni)
      #pragma unroll
      for (int i = 0; i < 4; ++i) {
        int row = gr0 + mi * 16 + kg * 4 + i;
        int col = w * 64 + ni * 16 + lr;
        local_[(size_t)row * HID + col] = gelu32(acc[mi][ni][i]);
      }
}

// ---------- K4: MFMA GEMM2  U = local @ W1; epilogue -> scores ----------
__global__ __launch_bounds__(256, 2) void k_g2(
    const float* __restrict__ local_,
    const _Float16* __restrict__ W1hT, const _Float16* __restrict__ W1lT,
    const float* __restrict__ W2, const float* __restrict__ c1,
    const float* __restrict__ c2, float* __restrict__ scores) {
  __shared__ _Float16 Ah[4][64][8], Al[4][64][8];
  __shared__ _Float16 Bh[4][256][8], Bl[4][256][8];
  __shared__ float red1[64][4], red2[64][4];
  const int tid = threadIdx.x, lane = tid & 63, w = tid >> 6;
  const int kg = lane >> 4, lr = lane & 15;
  const int gr0 = blockIdx.x * 64;
  const int arow = tid & 63, ag = tid >> 6;

  f32x4 acc[4][4];
  const f32x4 z4 = {0.f, 0.f, 0.f, 0.f};
  #pragma unroll
  for (int mi = 0; mi < 4; ++mi)
    #pragma unroll
    for (int ni = 0; ni < 4; ++ni) acc[mi][ni] = z4;

  for (int t = 0; t < 8; ++t) {
    const int kc = t * 32;
    float av[8];
    *(float4*)&av[0] = *(const float4*)&local_[(size_t)(gr0 + arow) * HID + kc + ag * 8];
    *(float4*)&av[4] = *(const float4*)&local_[(size_t)(gr0 + arow) * HID + kc + ag * 8 + 4];
    f16x8 wbh[4], wbl[4];
    #pragma unroll
    for (int gg = 0; gg < 4; ++gg) {
      wbh[gg] = *(const f16x8*)&W1hT[(size_t)tid * HID + kc + gg * 8];
      wbl[gg] = *(const f16x8*)&W1lT[(size_t)tid * HID + kc + gg * 8];
    }
    f16x8 ha, la;
    split8(av, ha, la);

    __syncthreads();
    *(f16x8*)&Ah[ag][arow][0] = ha;
    *(f16x8*)&Al[ag][arow][0] = la;
    #pragma unroll
    for (int gg = 0; gg < 4; ++gg) {
      *(f16x8*)&Bh[gg][tid][0] = wbh[gg];
      *(f16x8*)&Bl[gg][tid][0] = wbl[gg];
    }
    __syncthreads();

    f16x8 fah[4], fal[4], fbh[4], fbl[4];
    #pragma unroll
    for (int mi = 0; mi < 4; ++mi) {
      fah[mi] = *(const f16x8*)&Ah[kg][mi * 16 + lr][0];
      fal[mi] = *(const f16x8*)&Al[kg][mi * 16 + lr][0];
    }
    #pragma unroll
    for (int ni = 0; ni < 4; ++ni) {
      fbh[ni] = *(const f16x8*)&Bh[kg][w * 64 + ni * 16 + lr][0];
      fbl[ni] = *(const f16x8*)&Bl[kg][w * 64 + ni * 16 + lr][0];
    }
    #pragma unroll
    for (int mi = 0; mi < 4; ++mi)
      #pragma unroll
      for (int ni = 0; ni < 4; ++ni) {
        acc[mi][ni] = __builtin_amdgcn_mfma_f32_16x16x32_f16(fah[mi], fbh[ni], acc[mi][ni], 0, 0, 0);
        acc[mi][ni] = __builtin_amdgcn_mfma_f32_16x16x32_f16(fah[mi], fbl[ni], acc[mi][ni], 0, 0, 0);
        acc[mi][ni] = __builtin_amdgcn_mfma_f32_16x16x32_f16(fal[mi], fbh[ni], acc[mi][ni], 0, 0, 0);
      }
  }

  // epilogue: per-row  s = sum_col gelu(U + c) * W2
  float w2v[4];
  #pragma unroll
  for (int ni = 0; ni < 4; ++ni) w2v[ni] = W2[w * 64 + ni * 16 + lr];
  #pragma unroll
  for (int mi = 0; mi < 4; ++mi) {
    #pragma unroll
    for (int i = 0; i < 4; ++i) {
      int row = gr0 + mi * 16 + kg * 4 + i;
      int bf = row / NTOK;
      float p1 = 0.f, p2 = 0.f;
      #pragma unroll
      for (int ni = 0; ni < 4; ++ni) {
        int col = w * 64 + ni * 16 + lr;
        float u = acc[mi][ni][i];
        p1 = fmaf(gelu32(u + c1[(size_t)bf * HID + col]), w2v[ni], p1);
        p2 = fmaf(gelu32(u + c2[(size_t)bf * HID + col]), w2v[ni], p2);
      }
      #pragma unroll
      for (int m = 1; m < 16; m <<= 1) { p1 += __shfl_xor(p1, m); p2 += __shfl_xor(p2, m); }
      if (lr == 0) {
        red1[mi * 16 + kg * 4 + i][w] = p1;
        red2[mi * 16 + kg * 4 + i][w] = p2;
      }
    }
  }
  __syncthreads();
  if (tid < 64) {
    float s1 = red1[tid][0] + red1[tid][1] + red1[tid][2] + red1[tid][3];
    float s2 = red2[tid][0] + red2[tid][1] + red2[tid][2] + red2[tid][3];
    scores[gr0 + tid] = tanhf(s1) + tanhf(s2);
  }
}

// ---------- K5: perturbed top-k scatter, f32 keys, int counts ----------
__global__ __launch_bounds__(256) void k_topk(const float* __restrict__ scores,
                                              int* __restrict__ cnt) {
  int sid = blockIdx.x * 4 + (threadIdx.x >> 6);  // 0..47999
  int lane = threadIdx.x & 63;
  int b = sid / NS;
  unsigned key[4];
  #pragma unroll
  for (int c = 0; c < 4; ++c) {
    int j = c * 64 + lane;
    if (j < NTOK) {
      float n = noise_at((unsigned)sid * 196u + (unsigned)j);
      float p = fmaf(0.05f, n, scores[b * NTOK + j]);
      unsigned ub = __float_as_uint(p);
      key[c] = (ub & 0x80000000u) ? ~ub : (ub | 0x80000000u);
    } else {
      key[c] = 0u;
    }
  }
  unsigned prefix = 0u;
  for (int bit = 31; bit >= 0; --bit) {
    unsigned t = prefix | (1u << bit);
    int cn = 0;
    #pragma unroll
    for (int c = 0; c < 4; ++c) cn += __popcll(__ballot(key[c] >= t));
    if (cn >= TOPK) prefix = t;
  }
  unsigned long long mE[4];
  int cntG = 0;
  #pragma unroll
  for (int c = 0; c < 4; ++c) {
    cntG += __popcll(__ballot(key[c] > prefix));
    mE[c] = __ballot(key[c] == prefix);
  }
  int need = TOPK - cntG;
  unsigned long long lt = (1ull << lane) - 1ull;
  bool sel[4];
  #pragma unroll
  for (int c = 0; c < 4; ++c) {
    int er = 0;
    for (int cc = 0; cc < c; ++cc) er += __popcll(mE[cc]);
    er += __popcll(mE[c] & lt);
    sel[c] = (key[c] > prefix) || ((key[c] == prefix) && (er < need));
  }
  unsigned long long mS[4];
  #pragma unroll
  for (int c = 0; c < 4; ++c) mS[c] = __ballot(sel[c]);
  int base = 0;
  #pragma unroll
  for (int c = 0; c < 4; ++c) {
    if (sel[c]) {
      int rank = base + __popcll(mS[c] & lt);
      int j = c * 64 + lane;
      atomicAdd(&cnt[((size_t)b * TOPK + rank) * NTOK + j], 1);
    }
    base += __popcll(mS[c]);
  }
}

// ---------- K6: out[b,k,:] = sum_l (cnt/500) * x[b,l,:] ----------
__global__ __launch_bounds__(128) void k_out(const float* __restrict__ x,
                                             const int* __restrict__ cnt,
                                             float* __restrict__ out) {
  int bk = blockIdx.x;
  int b = bk / TOPK;
  __shared__ float sw[NTOK];
  for (int l = threadIdx.x; l < NTOK; l += 128)
    sw[l] = (float)cnt[(size_t)bk * NTOK + l] * 0.002f;
  __syncthreads();
  int d = threadIdx.x * 4;
  float a0 = 0, a1 = 0, a2 = 0, a3 = 0;
  for (int l = 0; l < NTOK; ++l) {
    float w = sw[l];
    if (w != 0.0f) {
      float4 xv = *(const float4*)(x + ((size_t)(b * NTOK + l)) * DIM + d);
      a0 = fmaf(w, xv.x, a0); a1 = fmaf(w, xv.y, a1);
      a2 = fmaf(w, xv.z, a2); a3 = fmaf(w, xv.w, a3);
    }
  }
  float4 o = {a0, a1, a2, a3};
  *(float4*)(out + (size_t)bk * DIM + d) = o;
}

// ---------- launcher ----------
extern "C" void kernel_launch(void* const* d_in, const int* in_sizes, int n_in,
                              void* d_out, int out_size, void* d_ws, size_t ws_size,
                              hipStream_t stream) {
  const float* x       = (const float*)d_in[0];
  const float* gf      = (const float*)d_in[1];
  const float* gs      = (const float*)d_in[2];
  const float* ln_in_g = (const float*)d_in[3];
  const float* ln_in_b = (const float*)d_in[4];
  const float* W_in    = (const float*)d_in[5];
  const float* ln_gd_g = (const float*)d_in[6];
  const float* ln_gd_b = (const float*)d_in[7];
  const float* W_gd    = (const float*)d_in[8];
  const float* W_out1  = (const float*)d_in[9];
  const float* W_out2  = (const float*)d_in[10];
  float* out = (float*)d_out;

  // ws layout (~24 MB)
  char* p = (char*)d_ws;
  float* local_ = (float*)p;      p += (size_t)ROWS * HID * 4;   // 19.27 MB
  int*   cnt    = (int*)p;        p += (size_t)BP * TOPK * NTOK * 4;
  float* stats  = (float*)p;      p += (size_t)ROWS * 2 * 4;
  float* c1     = (float*)p;      p += (size_t)BP * HID * 4;
  float* c2     = (float*)p;      p += (size_t)BP * HID * 4;
  float* scores = (float*)p;      p += (size_t)ROWS * 4;
  _Float16* WhT  = (_Float16*)p;  p += (size_t)HID * DIM * 2;
  _Float16* WlT  = (_Float16*)p;  p += (size_t)HID * DIM * 2;
  _Float16* W1hT = (_Float16*)p;  p += (size_t)HID * HID * 2;
  _Float16* W1lT = (_Float16*)p;  p += (size_t)HID * HID * 2;

  hipMemsetAsync(cnt, 0, (size_t)BP * TOPK * NTOK * sizeof(int), stream);
  k_glob<<<192, 256, 0, stream>>>(gf, gs, ln_gd_g, ln_gd_b, W_gd, W_out1, c1);
  k_prep<<<dim3(256, 2), 256, 0, stream>>>(W_in, W_out1, WhT, WlT, W1hT, W1lT);
  k_stats<<<ROWS / 4, 256, 0, stream>>>(x, stats);
  k_g1<<<GBLK, 256, 0, stream>>>(x, stats, ln_in_g, ln_in_b, WhT, WlT, local_);
  k_g2<<<GBLK, 256, 0, stream>>>(local_, W1hT, W1lT, W_out2, c1, c2, scores);
  k_topk<<<(BP * NS) / 4, 256, 0, stream>>>(scores, cnt);
  k_out<<<BP * TOPK, 128, 0, stream>>>(x, cnt, out);
}

// Round 9
// 338.579 us; speedup vs baseline: 1.5363x; 1.0531x over previous
//
#include <hip/hip_runtime.h>
#include <stdint.h>

#define DEV __device__ __forceinline__

// ---------- problem constants ----------
#define BP 96
#define NTOK 196
#define DIM 512
#define HID 256
#define NS 500
#define TOPK 49
#define ROWS (BP * NTOK)          // 18816
#define GBLK (ROWS / 64)          // 294 blocks for MFMA GEMMs
#define SPB 4                     // sample-chunks per frame-batch
#define CNTSZ (TOPK * NTOK)       // 9604

typedef _Float16 f16x8 __attribute__((ext_vector_type(8)));
typedef float f32x4 __attribute__((ext_vector_type(4)));

// ---------- math helpers ----------
DEV float gelu32(float v) {
  return 0.5f * v * (1.0f + erff(v * 0.70710678f));
}

DEV void split8(const float* v, f16x8& h, f16x8& l) {
  #pragma unroll
  for (int e = 0; e < 8; ++e) {
    _Float16 hh = (_Float16)v[e];
    h[e] = hh;
    l[e] = (_Float16)(v[e] - (float)hh);
  }
}

// Threefry-2x32, 20 rounds, key = (0, 1)  (jax.random.key(1))
DEV void threefry2x32(uint32_t x0, uint32_t x1, uint32_t& o0, uint32_t& o1) {
  const uint32_t k0 = 0u, k1 = 1u;
  const uint32_t k2 = 0x1BD11BDAu ^ k0 ^ k1;
  x0 += k0; x1 += k1;
#define TF_R(r) { x0 += x1; x1 = (x1 << (r)) | (x1 >> (32 - (r))); x1 ^= x0; }
  TF_R(13) TF_R(15) TF_R(26) TF_R(6)
  x0 += k1; x1 += k2 + 1u;
  TF_R(17) TF_R(29) TF_R(16) TF_R(24)
  x0 += k2; x1 += k0 + 2u;
  TF_R(13) TF_R(15) TF_R(26) TF_R(6)
  x0 += k0; x1 += k1 + 3u;
  TF_R(17) TF_R(29) TF_R(16) TF_R(24)
  x0 += k1; x1 += k2 + 4u;
  TF_R(13) TF_R(15) TF_R(26) TF_R(6)
  x0 += k2; x1 += k0 + 5u;
#undef TF_R
  o0 = x0; o1 = x1;
}

// XLA ErfInv32 (Giles polynomial)
DEV float erfinv_xla(float x) {
  float w = -log1pf(-x * x);
  float ws = w - 2.5f;
  float wl = sqrtf(w) - 3.0f;
  float ps = 2.81022636e-08f;
  ps = fmaf(ps, ws, 3.43273939e-07f);
  ps = fmaf(ps, ws, -3.5233877e-06f);
  ps = fmaf(ps, ws, -4.39150654e-06f);
  ps = fmaf(ps, ws, 0.00021858087f);
  ps = fmaf(ps, ws, -0.00125372503f);
  ps = fmaf(ps, ws, -0.00417768164f);
  ps = fmaf(ps, ws, 0.246640727f);
  ps = fmaf(ps, ws, 1.50140941f);
  float pl = -0.000200214257f;
  pl = fmaf(pl, wl, 0.000100950558f);
  pl = fmaf(pl, wl, 0.00134934322f);
  pl = fmaf(pl, wl, -0.00367342844f);
  pl = fmaf(pl, wl, 0.00573950773f);
  pl = fmaf(pl, wl, -0.0076224613f);
  pl = fmaf(pl, wl, 0.00943887047f);
  pl = fmaf(pl, wl, 1.00167406f);
  pl = fmaf(pl, wl, 2.83297682f);
  return (w < 5.0f ? ps : pl) * x;
}

// jax-f32-faithful N(0,1) noise, PARTITIONABLE threefry: counter=(0,g), draw=o0^o1
DEV float noise_at(unsigned g) {
  unsigned o0, o1;
  threefry2x32(0u, g, o0, o1);
  unsigned bits = o0 ^ o1;
  float f = __uint_as_float((bits >> 9) | 0x3f800000u) - 1.0f;
  float u = f * 2.0f - 0.99999994f;
  u = fmaxf(-0.99999994f, u);
  return 1.41421356f * erfinv_xla(u);
}

// ---------- K0: merged pre-pass: glob (192) | wprep (512) | stats (4704) ----------
#define PRE_GLOB 192
#define PRE_PREP 512
#define PRE_STATS (ROWS / 4)
__global__ __launch_bounds__(256) void k_pre(
    const float* __restrict__ gf, const float* __restrict__ gs,
    const float* __restrict__ lng, const float* __restrict__ lnb,
    const float* __restrict__ Wgd, const float* __restrict__ Wout1,
    float* __restrict__ cout,
    const float* __restrict__ Win,
    _Float16* __restrict__ WhT, _Float16* __restrict__ WlT,
    _Float16* __restrict__ W1hT, _Float16* __restrict__ W1lT,
    const float* __restrict__ x, float* __restrict__ stats) {
  const int bid = blockIdx.x;
  if (bid < PRE_GLOB) {
    // ---- guidance constants c1,c2 ----
    int bq = bid >> 1, which = bid & 1;
    const float* row = which ? (gs + (size_t)(bq / 12) * DIM) : (gf + (size_t)bq * DIM);
    __shared__ float lx[DIM];
    __shared__ float sg[HID];
    __shared__ double sred[8];
    int tid = threadIdx.x, lane = tid & 63, wv = tid >> 6;
    float v0 = row[tid], v1 = row[tid + 256];
    double s = (double)v0 + v1, q = (double)v0 * v0 + (double)v1 * v1;
    #pragma unroll
    for (int m = 1; m < 64; m <<= 1) { s += __shfl_xor(s, m); q += __shfl_xor(q, m); }
    if (lane == 0) { sred[wv * 2] = s; sred[wv * 2 + 1] = q; }
    __syncthreads();
    double ts = sred[0] + sred[2] + sred[4] + sred[6];
    double tq = sred[1] + sred[3] + sred[5] + sred[7];
    double mean = ts / 512.0;
    double var = tq / 512.0 - mean * mean;
    float mn = (float)mean;
    float rs = (float)(1.0 / sqrt(var + 1e-5));
    lx[tid]       = (v0 - mn) * rs * lng[tid] + lnb[tid];
    lx[tid + 256] = (v1 - mn) * rs * lng[tid + 256] + lnb[tid + 256];
    __syncthreads();
    float acc = 0.0f;
    for (int d = 0; d < DIM; ++d) acc = fmaf(lx[d], Wgd[(size_t)d * HID + tid], acc);
    sg[tid] = gelu32(acc);
    __syncthreads();
    float c = 0.0f;
    for (int j = 0; j < HID; ++j) c = fmaf(sg[j], Wout1[(size_t)(HID + j) * HID + tid], c);
    cout[((size_t)which * BP + bq) * HID + tid] = c;
  } else if (bid < PRE_GLOB + PRE_PREP) {
    // ---- weight transpose + fp16 split ----
    int b2 = bid - PRE_GLOB;
    int n = b2 & 255, half = b2 >> 8;
    if (half == 0) {
      for (int k = threadIdx.x; k < DIM; k += 256) {
        float v = Win[(size_t)k * HID + n];
        _Float16 h = (_Float16)v;
        WhT[(size_t)n * DIM + k] = h;
        WlT[(size_t)n * DIM + k] = (_Float16)(v - (float)h);
      }
    } else {
      int k = threadIdx.x;
      float v = Wout1[(size_t)k * HID + n];
      _Float16 h = (_Float16)v;
      W1hT[(size_t)n * HID + k] = h;
      W1lT[(size_t)n * HID + k] = (_Float16)(v - (float)h);
    }
  } else {
    // ---- per-row LN stats of x ----
    int r = (bid - PRE_GLOB - PRE_PREP) * 4 + (threadIdx.x >> 6);
    int lane = threadIdx.x & 63;
    const float4* xr = (const float4*)(x + (size_t)r * DIM);
    float4 a = xr[lane], c = xr[lane + 64];
    double s = (double)a.x + a.y + a.z + a.w + (double)c.x + c.y + c.z + c.w;
    double q = (double)a.x * a.x + (double)a.y * a.y + (double)a.z * a.z + (double)a.w * a.w +
               (double)c.x * c.x + (double)c.y * c.y + (double)c.z * c.z + (double)c.w * c.w;
    #pragma unroll
    for (int m = 1; m < 64; m <<= 1) { s += __shfl_xor(s, m); q += __shfl_xor(q, m); }
    if (lane == 0) {
      double mean = s / 512.0;
      double var = q / 512.0 - mean * mean;
      stats[r * 2]     = (float)mean;
      stats[r * 2 + 1] = (float)(1.0 / sqrt(var + 1e-5));
    }
  }
}

// ---------- K1: MFMA GEMM1  local = gelu(LN(x)g+b @ Win)  [fp16 split x3] ----------
__global__ __launch_bounds__(256, 2) void k_g1(
    const float* __restrict__ x, const float* __restrict__ stats,
    const float* __restrict__ g_in, const float* __restrict__ b_in,
    const _Float16* __restrict__ WhT, const _Float16* __restrict__ WlT,
    float* __restrict__ local_) {
  __shared__ _Float16 Ah[4][64][8], Al[4][64][8];     // 4KB + 4KB
  __shared__ _Float16 Bh[4][256][8], Bl[4][256][8];   // 16KB + 16KB
  const int tid = threadIdx.x, lane = tid & 63, w = tid >> 6;
  const int kg = lane >> 4, lr = lane & 15;
  const int gr0 = blockIdx.x * 64;
  const int arow = tid & 63, ag = tid >> 6;
  const float mn = stats[(gr0 + arow) * 2], rs = stats[(gr0 + arow) * 2 + 1];

  f32x4 acc[4][4];
  const f32x4 z4 = {0.f, 0.f, 0.f, 0.f};
  #pragma unroll
  for (int mi = 0; mi < 4; ++mi)
    #pragma unroll
    for (int ni = 0; ni < 4; ++ni) acc[mi][ni] = z4;

  for (int t = 0; t < 16; ++t) {
    const int kc = t * 32;
    float xv[8], gv[8], bv[8];
    *(float4*)&xv[0] = *(const float4*)&x[(size_t)(gr0 + arow) * DIM + kc + ag * 8];
    *(float4*)&xv[4] = *(const float4*)&x[(size_t)(gr0 + arow) * DIM + kc + ag * 8 + 4];
    *(float4*)&gv[0] = *(const float4*)&g_in[kc + ag * 8];
    *(float4*)&gv[4] = *(const float4*)&g_in[kc + ag * 8 + 4];
    *(float4*)&bv[0] = *(const float4*)&b_in[kc + ag * 8];
    *(float4*)&bv[4] = *(const float4*)&b_in[kc + ag * 8 + 4];
    f16x8 wbh[4], wbl[4];
    #pragma unroll
    for (int gg = 0; gg < 4; ++gg) {
      wbh[gg] = *(const f16x8*)&WhT[(size_t)tid * DIM + kc + gg * 8];
      wbl[gg] = *(const f16x8*)&WlT[(size_t)tid * DIM + kc + gg * 8];
    }
    float xnv[8];
    #pragma unroll
    for (int e = 0; e < 8; ++e) xnv[e] = fmaf((xv[e] - mn) * rs, gv[e], bv[e]);
    f16x8 ha, la;
    split8(xnv, ha, la);

    __syncthreads();
    *(f16x8*)&Ah[ag][arow][0] = ha;
    *(f16x8*)&Al[ag][arow][0] = la;
    #pragma unroll
    for (int gg = 0; gg < 4; ++gg) {
      *(f16x8*)&Bh[gg][tid][0] = wbh[gg];
      *(f16x8*)&Bl[gg][tid][0] = wbl[gg];
    }
    __syncthreads();

    f16x8 fah[4], fal[4], fbh[4], fbl[4];
    #pragma unroll
    for (int mi = 0; mi < 4; ++mi) {
      fah[mi] = *(const f16x8*)&Ah[kg][mi * 16 + lr][0];
      fal[mi] = *(const f16x8*)&Al[kg][mi * 16 + lr][0];
    }
    #pragma unroll
    for (int ni = 0; ni < 4; ++ni) {
      fbh[ni] = *(const f16x8*)&Bh[kg][w * 64 + ni * 16 + lr][0];
      fbl[ni] = *(const f16x8*)&Bl[kg][w * 64 + ni * 16 + lr][0];
    }
    #pragma unroll
    for (int mi = 0; mi < 4; ++mi)
      #pragma unroll
      for (int ni = 0; ni < 4; ++ni) {
        acc[mi][ni] = __builtin_amdgcn_mfma_f32_16x16x32_f16(fah[mi], fbh[ni], acc[mi][ni], 0, 0, 0);
        acc[mi][ni] = __builtin_amdgcn_mfma_f32_16x16x32_f16(fah[mi], fbl[ni], acc[mi][ni], 0, 0, 0);
        acc[mi][ni] = __builtin_amdgcn_mfma_f32_16x16x32_f16(fal[mi], fbh[ni], acc[mi][ni], 0, 0, 0);
      }
  }

  #pragma unroll
  for (int mi = 0; mi < 4; ++mi)
    #pragma unroll
    for (int ni = 0; ni < 4; ++ni)
      #pragma unroll
      for (int i = 0; i < 4; ++i) {
        int row = gr0 + mi * 16 + kg * 4 + i;
        int col = w * 64 + ni * 16 + lr;
        local_[(size_t)row * HID + col] = gelu32(acc[mi][ni][i]);
      }
}

// ---------- K2: MFMA GEMM2  U = local @ W1; epilogue -> scores ----------
__global__ __launch_bounds__(256, 2) void k_g2(
    const float* __restrict__ local_,
    const _Float16* __restrict__ W1hT, const _Float16* __restrict__ W1lT,
    const float* __restrict__ W2, const float* __restrict__ c1,
    const float* __restrict__ c2, float* __restrict__ scores) {
  __shared__ _Float16 Ah[4][64][8], Al[4][64][8];
  __shared__ _Float16 Bh[4][256][8], Bl[4][256][8];
  __shared__ float red1[64][4], red2[64][4];
  const int tid = threadIdx.x, lane = tid & 63, w = tid >> 6;
  const int kg = lane >> 4, lr = lane & 15;
  const int gr0 = blockIdx.x * 64;
  const int arow = tid & 63, ag = tid >> 6;

  f32x4 acc[4][4];
  const f32x4 z4 = {0.f, 0.f, 0.f, 0.f};
  #pragma unroll
  for (int mi = 0; mi < 4; ++mi)
    #pragma unroll
    for (int ni = 0; ni < 4; ++ni) acc[mi][ni] = z4;

  for (int t = 0; t < 8; ++t) {
    const int kc = t * 32;
    float av[8];
    *(float4*)&av[0] = *(const float4*)&local_[(size_t)(gr0 + arow) * HID + kc + ag * 8];
    *(float4*)&av[4] = *(const float4*)&local_[(size_t)(gr0 + arow) * HID + kc + ag * 8 + 4];
    f16x8 wbh[4], wbl[4];
    #pragma unroll
    for (int gg = 0; gg < 4; ++gg) {
      wbh[gg] = *(const f16x8*)&W1hT[(size_t)tid * HID + kc + gg * 8];
      wbl[gg] = *(const f16x8*)&W1lT[(size_t)tid * HID + kc + gg * 8];
    }
    f16x8 ha, la;
    split8(av, ha, la);

    __syncthreads();
    *(f16x8*)&Ah[ag][arow][0] = ha;
    *(f16x8*)&Al[ag][arow][0] = la;
    #pragma unroll
    for (int gg = 0; gg < 4; ++gg) {
      *(f16x8*)&Bh[gg][tid][0] = wbh[gg];
      *(f16x8*)&Bl[gg][tid][0] = wbl[gg];
    }
    __syncthreads();

    f16x8 fah[4], fal[4], fbh[4], fbl[4];
    #pragma unroll
    for (int mi = 0; mi < 4; ++mi) {
      fah[mi] = *(const f16x8*)&Ah[kg][mi * 16 + lr][0];
      fal[mi] = *(const f16x8*)&Al[kg][mi * 16 + lr][0];
    }
    #pragma unroll
    for (int ni = 0; ni < 4; ++ni) {
      fbh[ni] = *(const f16x8*)&Bh[kg][w * 64 + ni * 16 + lr][0];
      fbl[ni] = *(const f16x8*)&Bl[kg][w * 64 + ni * 16 + lr][0];
    }
    #pragma unroll
    for (int mi = 0; mi < 4; ++mi)
      #pragma unroll
      for (int ni = 0; ni < 4; ++ni) {
        acc[mi][ni] = __builtin_amdgcn_mfma_f32_16x16x32_f16(fah[mi], fbh[ni], acc[mi][ni], 0, 0, 0);
        acc[mi][ni] = __builtin_amdgcn_mfma_f32_16x16x32_f16(fah[mi], fbl[ni], acc[mi][ni], 0, 0, 0);
        acc[mi][ni] = __builtin_amdgcn_mfma_f32_16x16x32_f16(fal[mi], fbh[ni], acc[mi][ni], 0, 0, 0);
      }
  }

  float w2v[4];
  #pragma unroll
  for (int ni = 0; ni < 4; ++ni) w2v[ni] = W2[w * 64 + ni * 16 + lr];
  #pragma unroll
  for (int mi = 0; mi < 4; ++mi) {
    #pragma unroll
    for (int i = 0; i < 4; ++i) {
      int row = gr0 + mi * 16 + kg * 4 + i;
      int bf = row / NTOK;
      float p1 = 0.f, p2 = 0.f;
      #pragma unroll
      for (int ni = 0; ni < 4; ++ni) {
        int col = w * 64 + ni * 16 + lr;
        float u = acc[mi][ni][i];
        p1 = fmaf(gelu32(u + c1[(size_t)bf * HID + col]), w2v[ni], p1);
        p2 = fmaf(gelu32(u + c2[(size_t)bf * HID + col]), w2v[ni], p2);
      }
      #pragma unroll
      for (int m = 1; m < 16; m <<= 1) { p1 += __shfl_xor(p1, m); p2 += __shfl_xor(p2, m); }
      if (lr == 0) {
        red1[mi * 16 + kg * 4 + i][w] = p1;
        red2[mi * 16 + kg * 4 + i][w] = p2;
      }
    }
  }
  __syncthreads();
  if (tid < 64) {
    float s1 = red1[tid][0] + red1[tid][1] + red1[tid][2] + red1[tid][3];
    float s2 = red2[tid][0] + red2[tid][1] + red2[tid][2] + red2[tid][3];
    scores[gr0 + tid] = tanhf(s1) + tanhf(s2);
  }
}

// ---------- K3: perturbed top-k, LDS-accumulated partial counts ----------
// grid (96, SPB), 512 threads = 8 waves; wave handles samples s ≡ chunk+8*wv (mod 64)
__global__ __launch_bounds__(512) void k_topk(const float* __restrict__ scores,
                                              int* __restrict__ partial) {
  const int b = blockIdx.x, chunk = blockIdx.y;
  const int tid = threadIdx.x, lane = tid & 63, wv = tid >> 6;
  __shared__ float sc_s[NTOK];
  __shared__ int cnt_s[CNTSZ];
  if (tid < NTOK) sc_s[tid] = scores[b * NTOK + tid];
  for (int i = tid; i < CNTSZ; i += 512) cnt_s[i] = 0;
  __syncthreads();

  for (int s = chunk + SPB * wv; s < NS; s += SPB * 8) {
    const int sid = b * NS + s;
    unsigned key[4];
    #pragma unroll
    for (int c = 0; c < 4; ++c) {
      int j = c * 64 + lane;
      if (j < NTOK) {
        float n = noise_at((unsigned)sid * 196u + (unsigned)j);
        float p = fmaf(0.05f, n, sc_s[j]);
        unsigned ub = __float_as_uint(p);
        key[c] = (ub & 0x80000000u) ? ~ub : (ub | 0x80000000u);
      } else {
        key[c] = 0u;
      }
    }
    unsigned prefix = 0u;
    for (int bit = 31; bit >= 0; --bit) {
      unsigned t = prefix | (1u << bit);
      int cn = 0;
      #pragma unroll
      for (int c = 0; c < 4; ++c) cn += __popcll(__ballot(key[c] >= t));
      if (cn >= TOPK) prefix = t;
    }
    unsigned long long mE[4];
    int cntG = 0;
    #pragma unroll
    for (int c = 0; c < 4; ++c) {
      cntG += __popcll(__ballot(key[c] > prefix));
      mE[c] = __ballot(key[c] == prefix);
    }
    int need = TOPK - cntG;
    unsigned long long lt = (1ull << lane) - 1ull;
    bool sel[4];
    #pragma unroll
    for (int c = 0; c < 4; ++c) {
      int er = 0;
      for (int cc = 0; cc < c; ++cc) er += __popcll(mE[cc]);
      er += __popcll(mE[c] & lt);
      sel[c] = (key[c] > prefix) || ((key[c] == prefix) && (er < need));
    }
    unsigned long long mS[4];
    #pragma unroll
    for (int c = 0; c < 4; ++c) mS[c] = __ballot(sel[c]);
    int base = 0;
    #pragma unroll
    for (int c = 0; c < 4; ++c) {
      if (sel[c]) {
        int rank = base + __popcll(mS[c] & lt);
        int j = c * 64 + lane;
        atomicAdd(&cnt_s[rank * NTOK + j], 1);
      }
      base += __popcll(mS[c]);
    }
  }
  __syncthreads();
  int* dst = partial + ((size_t)b * SPB + chunk) * CNTSZ;
  for (int i = tid; i < CNTSZ; i += 512) dst[i] = cnt_s[i];
}

// ---------- K4: out[b,k,:] = sum_l (sum_c partial)/500 * x[b,l,:] ----------
__global__ __launch_bounds__(128) void k_out(const float* __restrict__ x,
                                             const int* __restrict__ partial,
                                             float* __restrict__ out) {
  int bk = blockIdx.x;
  int b = bk / TOPK, k = bk - b * TOPK;
  __shared__ float sw[NTOK];
  for (int l = threadIdx.x; l < NTOK; l += 128) {
    int c = 0;
    #pragma unroll
    for (int cc = 0; cc < SPB; ++cc)
      c += partial[((size_t)b * SPB + cc) * CNTSZ + k * NTOK + l];
    sw[l] = (float)c * 0.002f;
  }
  __syncthreads();
  int d = threadIdx.x * 4;
  float a0 = 0, a1 = 0, a2 = 0, a3 = 0;
  for (int l = 0; l < NTOK; ++l) {
    float w = sw[l];
    if (w != 0.0f) {
      float4 xv = *(const float4*)(x + ((size_t)(b * NTOK + l)) * DIM + d);
      a0 = fmaf(w, xv.x, a0); a1 = fmaf(w, xv.y, a1);
      a2 = fmaf(w, xv.z, a2); a3 = fmaf(w, xv.w, a3);
    }
  }
  float4 o = {a0, a1, a2, a3};
  *(float4*)(out + (size_t)bk * DIM + d) = o;
}

// ---------- launcher ----------
extern "C" void kernel_launch(void* const* d_in, const int* in_sizes, int n_in,
                              void* d_out, int out_size, void* d_ws, size_t ws_size,
                              hipStream_t stream) {
  const float* x       = (const float*)d_in[0];
  const float* gf      = (const float*)d_in[1];
  const float* gs      = (const float*)d_in[2];
  const float* ln_in_g = (const float*)d_in[3];
  const float* ln_in_b = (const float*)d_in[4];
  const float* W_in    = (const float*)d_in[5];
  const float* ln_gd_g = (const float*)d_in[6];
  const float* ln_gd_b = (const float*)d_in[7];
  const float* W_gd    = (const float*)d_in[8];
  const float* W_out1  = (const float*)d_in[9];
  const float* W_out2  = (const float*)d_in[10];
  float* out = (float*)d_out;

  // ws layout (~37 MB)
  char* p = (char*)d_ws;
  float* local_  = (float*)p;     p += (size_t)ROWS * HID * 4;          // 19.3 MB
  int*   partial = (int*)p;       p += (size_t)BP * SPB * CNTSZ * 4;    // 14.7 MB
  float* stats   = (float*)p;     p += (size_t)ROWS * 2 * 4;
  float* c1      = (float*)p;     p += (size_t)BP * HID * 4;
  float* c2      = (float*)p;     p += (size_t)BP * HID * 4;
  float* scores  = (float*)p;     p += (size_t)ROWS * 4;
  _Float16* WhT  = (_Float16*)p;  p += (size_t)HID * DIM * 2;
  _Float16* WlT  = (_Float16*)p;  p += (size_t)HID * DIM * 2;
  _Float16* W1hT = (_Float16*)p;  p += (size_t)HID * HID * 2;
  _Float16* W1lT = (_Float16*)p;  p += (size_t)HID * HID * 2;

  k_pre<<<PRE_GLOB + PRE_PREP + PRE_STATS, 256, 0, stream>>>(
      gf, gs, ln_gd_g, ln_gd_b, W_gd, W_out1, c1,
      W_in, WhT, WlT, W1hT, W1lT, x, stats);
  k_g1<<<GBLK, 256, 0, stream>>>(x, stats, ln_in_g, ln_in_b, WhT, WlT, local_);
  k_g2<<<GBLK, 256, 0, stream>>>(local_, W1hT, W1lT, W_out2, c1, c2, scores);
  k_topk<<<dim3(BP, SPB), 512, 0, stream>>>(scores, partial);
  k_out<<<BP * TOPK, 128, 0, stream>>>(x, partial, out);
}

// Round 10
// 266.174 us; speedup vs baseline: 1.9542x; 1.2720x over previous
//
#include <hip/hip_runtime.h>
#include <stdint.h>

#define DEV __device__ __forceinline__

// ---------- problem constants ----------
#define BP 96
#define NTOK 196
#define DIM 512
#define HID 256
#define NS 500
#define TOPK 49
#define ROWS (BP * NTOK)          // 18816
#define GBLK (ROWS / 64)          // 294 blocks for MFMA GEMMs
#define SPB 8                     // sample-chunks per frame-batch
#define CNTSZ (TOPK * NTOK)       // 9604

typedef _Float16 f16x8 __attribute__((ext_vector_type(8)));
typedef float f32x4 __attribute__((ext_vector_type(4)));

// ---------- math helpers ----------
DEV float gelu32(float v) {
  return 0.5f * v * (1.0f + erff(v * 0.70710678f));
}

DEV void split8(const float* v, f16x8& h, f16x8& l) {
  #pragma unroll
  for (int e = 0; e < 8; ++e) {
    _Float16 hh = (_Float16)v[e];
    h[e] = hh;
    l[e] = (_Float16)(v[e] - (float)hh);
  }
}

// Threefry-2x32, 20 rounds, key = (0, 1)  (jax.random.key(1))
DEV void threefry2x32(uint32_t x0, uint32_t x1, uint32_t& o0, uint32_t& o1) {
  const uint32_t k0 = 0u, k1 = 1u;
  const uint32_t k2 = 0x1BD11BDAu ^ k0 ^ k1;
  x0 += k0; x1 += k1;
#define TF_R(r) { x0 += x1; x1 = (x1 << (r)) | (x1 >> (32 - (r))); x1 ^= x0; }
  TF_R(13) TF_R(15) TF_R(26) TF_R(6)
  x0 += k1; x1 += k2 + 1u;
  TF_R(17) TF_R(29) TF_R(16) TF_R(24)
  x0 += k2; x1 += k0 + 2u;
  TF_R(13) TF_R(15) TF_R(26) TF_R(6)
  x0 += k0; x1 += k1 + 3u;
  TF_R(17) TF_R(29) TF_R(16) TF_R(24)
  x0 += k1; x1 += k2 + 4u;
  TF_R(13) TF_R(15) TF_R(26) TF_R(6)
  x0 += k2; x1 += k0 + 5u;
#undef TF_R
  o0 = x0; o1 = x1;
}

// XLA ErfInv32 (Giles polynomial); rare branch computed only when a lane needs it
DEV float erfinv_xla(float x) {
  float w = -log1pf(-x * x);
  float ws = w - 2.5f;
  float ps = 2.81022636e-08f;
  ps = fmaf(ps, ws, 3.43273939e-07f);
  ps = fmaf(ps, ws, -3.5233877e-06f);
  ps = fmaf(ps, ws, -4.39150654e-06f);
  ps = fmaf(ps, ws, 0.00021858087f);
  ps = fmaf(ps, ws, -0.00125372503f);
  ps = fmaf(ps, ws, -0.00417768164f);
  ps = fmaf(ps, ws, 0.246640727f);
  ps = fmaf(ps, ws, 1.50140941f);
  float r = ps;
  if (__ballot(w >= 5.0f) != 0ull) {        // wave-uniform skip of the rare path
    float wl = sqrtf(w) - 3.0f;
    float pl = -0.000200214257f;
    pl = fmaf(pl, wl, 0.000100950558f);
    pl = fmaf(pl, wl, 0.00134934322f);
    pl = fmaf(pl, wl, -0.00367342844f);
    pl = fmaf(pl, wl, 0.00573950773f);
    pl = fmaf(pl, wl, -0.0076224613f);
    pl = fmaf(pl, wl, 0.00943887047f);
    pl = fmaf(pl, wl, 1.00167406f);
    pl = fmaf(pl, wl, 2.83297682f);
    r = (w < 5.0f) ? ps : pl;
  }
  return r * x;
}

// jax-f32-faithful N(0,1) noise, PARTITIONABLE threefry: counter=(0,g), draw=o0^o1
DEV float noise_at(unsigned g) {
  unsigned o0, o1;
  threefry2x32(0u, g, o0, o1);
  unsigned bits = o0 ^ o1;
  float f = __uint_as_float((bits >> 9) | 0x3f800000u) - 1.0f;
  float u = f * 2.0f - 0.99999994f;
  u = fmaxf(-0.99999994f, u);
  return 1.41421356f * erfinv_xla(u);
}

// ---------- K0: merged pre-pass: glob (192) | wprep (512) | stats (4704) ----------
#define PRE_GLOB 192
#define PRE_PREP 512
#define PRE_STATS (ROWS / 4)
__global__ __launch_bounds__(256) void k_pre(
    const float* __restrict__ gf, const float* __restrict__ gs,
    const float* __restrict__ lng, const float* __restrict__ lnb,
    const float* __restrict__ Wgd, const float* __restrict__ Wout1,
    float* __restrict__ cout,
    const float* __restrict__ Win,
    _Float16* __restrict__ WhT, _Float16* __restrict__ WlT,
    _Float16* __restrict__ W1hT, _Float16* __restrict__ W1lT,
    const float* __restrict__ x, float* __restrict__ stats) {
  const int bid = blockIdx.x;
  if (bid < PRE_GLOB) {
    int bq = bid >> 1, which = bid & 1;
    const float* row = which ? (gs + (size_t)(bq / 12) * DIM) : (gf + (size_t)bq * DIM);
    __shared__ float lx[DIM];
    __shared__ float sg[HID];
    __shared__ double sred[8];
    int tid = threadIdx.x, lane = tid & 63, wv = tid >> 6;
    float v0 = row[tid], v1 = row[tid + 256];
    double s = (double)v0 + v1, q = (double)v0 * v0 + (double)v1 * v1;
    #pragma unroll
    for (int m = 1; m < 64; m <<= 1) { s += __shfl_xor(s, m); q += __shfl_xor(q, m); }
    if (lane == 0) { sred[wv * 2] = s; sred[wv * 2 + 1] = q; }
    __syncthreads();
    double ts = sred[0] + sred[2] + sred[4] + sred[6];
    double tq = sred[1] + sred[3] + sred[5] + sred[7];
    double mean = ts / 512.0;
    double var = tq / 512.0 - mean * mean;
    float mn = (float)mean;
    float rs = (float)(1.0 / sqrt(var + 1e-5));
    lx[tid]       = (v0 - mn) * rs * lng[tid] + lnb[tid];
    lx[tid + 256] = (v1 - mn) * rs * lng[tid + 256] + lnb[tid + 256];
    __syncthreads();
    float acc = 0.0f;
    for (int d = 0; d < DIM; ++d) acc = fmaf(lx[d], Wgd[(size_t)d * HID + tid], acc);
    sg[tid] = gelu32(acc);
    __syncthreads();
    float c = 0.0f;
    for (int j = 0; j < HID; ++j) c = fmaf(sg[j], Wout1[(size_t)(HID + j) * HID + tid], c);
    cout[((size_t)which * BP + bq) * HID + tid] = c;
  } else if (bid < PRE_GLOB + PRE_PREP) {
    int b2 = bid - PRE_GLOB;
    int n = b2 & 255, half = b2 >> 8;
    if (half == 0) {
      for (int k = threadIdx.x; k < DIM; k += 256) {
        float v = Win[(size_t)k * HID + n];
        _Float16 h = (_Float16)v;
        WhT[(size_t)n * DIM + k] = h;
        WlT[(size_t)n * DIM + k] = (_Float16)(v - (float)h);
      }
    } else {
      int k = threadIdx.x;
      float v = Wout1[(size_t)k * HID + n];
      _Float16 h = (_Float16)v;
      W1hT[(size_t)n * HID + k] = h;
      W1lT[(size_t)n * HID + k] = (_Float16)(v - (float)h);
    }
  } else {
    int r = (bid - PRE_GLOB - PRE_PREP) * 4 + (threadIdx.x >> 6);
    int lane = threadIdx.x & 63;
    const float4* xr = (const float4*)(x + (size_t)r * DIM);
    float4 a = xr[lane], c = xr[lane + 64];
    double s = (double)a.x + a.y + a.z + a.w + (double)c.x + c.y + c.z + c.w;
    double q = (double)a.x * a.x + (double)a.y * a.y + (double)a.z * a.z + (double)a.w * a.w +
               (double)c.x * c.x + (double)c.y * c.y + (double)c.z * c.z + (double)c.w * c.w;
    #pragma unroll
    for (int m = 1; m < 64; m <<= 1) { s += __shfl_xor(s, m); q += __shfl_xor(q, m); }
    if (lane == 0) {
      double mean = s / 512.0;
      double var = q / 512.0 - mean * mean;
      stats[r * 2]     = (float)mean;
      stats[r * 2 + 1] = (float)(1.0 / sqrt(var + 1e-5));
    }
  }
}

// ---------- K1: MFMA GEMM1  local = gelu(LN(x)g+b @ Win)  [fp16 split x3] ----------
__global__ __launch_bounds__(256, 2) void k_g1(
    const float* __restrict__ x, const float* __restrict__ stats,
    const float* __restrict__ g_in, const float* __restrict__ b_in,
    const _Float16* __restrict__ WhT, const _Float16* __restrict__ WlT,
    float* __restrict__ local_) {
  __shared__ _Float16 Ah[4][64][8], Al[4][64][8];     // 4KB + 4KB
  __shared__ _Float16 Bh[4][256][8], Bl[4][256][8];   // 16KB + 16KB
  const int tid = threadIdx.x, lane = tid & 63, w = tid >> 6;
  const int kg = lane >> 4, lr = lane & 15;
  const int gr0 = blockIdx.x * 64;
  const int arow = tid & 63, ag = tid >> 6;
  const float mn = stats[(gr0 + arow) * 2], rs = stats[(gr0 + arow) * 2 + 1];

  f32x4 acc[4][4];
  const f32x4 z4 = {0.f, 0.f, 0.f, 0.f};
  #pragma unroll
  for (int mi = 0; mi < 4; ++mi)
    #pragma unroll
    for (int ni = 0; ni < 4; ++ni) acc[mi][ni] = z4;

  for (int t = 0; t < 16; ++t) {
    const int kc = t * 32;
    float xv[8], gv[8], bv[8];
    *(float4*)&xv[0] = *(const float4*)&x[(size_t)(gr0 + arow) * DIM + kc + ag * 8];
    *(float4*)&xv[4] = *(const float4*)&x[(size_t)(gr0 + arow) * DIM + kc + ag * 8 + 4];
    *(float4*)&gv[0] = *(const float4*)&g_in[kc + ag * 8];
    *(float4*)&gv[4] = *(const float4*)&g_in[kc + ag * 8 + 4];
    *(float4*)&bv[0] = *(const float4*)&b_in[kc + ag * 8];
    *(float4*)&bv[4] = *(const float4*)&b_in[kc + ag * 8 + 4];
    f16x8 wbh[4], wbl[4];
    #pragma unroll
    for (int gg = 0; gg < 4; ++gg) {
      wbh[gg] = *(const f16x8*)&WhT[(size_t)tid * DIM + kc + gg * 8];
      wbl[gg] = *(const f16x8*)&WlT[(size_t)tid * DIM + kc + gg * 8];
    }
    float xnv[8];
    #pragma unroll
    for (int e = 0; e < 8; ++e) xnv[e] = fmaf((xv[e] - mn) * rs, gv[e], bv[e]);
    f16x8 ha, la;
    split8(xnv, ha, la);

    __syncthreads();
    *(f16x8*)&Ah[ag][arow][0] = ha;
    *(f16x8*)&Al[ag][arow][0] = la;
    #pragma unroll
    for (int gg = 0; gg < 4; ++gg) {
      *(f16x8*)&Bh[gg][tid][0] = wbh[gg];
      *(f16x8*)&Bl[gg][tid][0] = wbl[gg];
    }
    __syncthreads();

    f16x8 fah[4], fal[4], fbh[4], fbl[4];
    #pragma unroll
    for (int mi = 0; mi < 4; ++mi) {
      fah[mi] = *(const f16x8*)&Ah[kg][mi * 16 + lr][0];
      fal[mi] = *(const f16x8*)&Al[kg][mi * 16 + lr][0];
    }
    #pragma unroll
    for (int ni = 0; ni < 4; ++ni) {
      fbh[ni] = *(const f16x8*)&Bh[kg][w * 64 + ni * 16 + lr][0];
      fbl[ni] = *(const f16x8*)&Bl[kg][w * 64 + ni * 16 + lr][0];
    }
    #pragma unroll
    for (int mi = 0; mi < 4; ++mi)
      #pragma unroll
      for (int ni = 0; ni < 4; ++ni) {
        acc[mi][ni] = __builtin_amdgcn_mfma_f32_16x16x32_f16(fah[mi], fbh[ni], acc[mi][ni], 0, 0, 0);
        acc[mi][ni] = __builtin_amdgcn_mfma_f32_16x16x32_f16(fah[mi], fbl[ni], acc[mi][ni], 0, 0, 0);
        acc[mi][ni] = __builtin_amdgcn_mfma_f32_16x16x32_f16(fal[mi], fbh[ni], acc[mi][ni], 0, 0, 0);
      }
  }

  #pragma unroll
  for (int mi = 0; mi < 4; ++mi)
    #pragma unroll
    for (int ni = 0; ni < 4; ++ni)
      #pragma unroll
      for (int i = 0; i < 4; ++i) {
        int row = gr0 + mi * 16 + kg * 4 + i;
        int col = w * 64 + ni * 16 + lr;
        local_[(size_t)row * HID + col] = gelu32(acc[mi][ni][i]);
      }
}

// ---------- K2: MFMA GEMM2  U = local @ W1; epilogue -> scores ----------
__global__ __launch_bounds__(256, 2) void k_g2(
    const float* __restrict__ local_,
    const _Float16* __restrict__ W1hT, const _Float16* __restrict__ W1lT,
    const float* __restrict__ W2, const float* __restrict__ c1,
    const float* __restrict__ c2, float* __restrict__ scores) {
  __shared__ _Float16 Ah[4][64][8], Al[4][64][8];
  __shared__ _Float16 Bh[4][256][8], Bl[4][256][8];
  __shared__ float red1[64][4], red2[64][4];
  const int tid = threadIdx.x, lane = tid & 63, w = tid >> 6;
  const int kg = lane >> 4, lr = lane & 15;
  const int gr0 = blockIdx.x * 64;
  const int arow = tid & 63, ag = tid >> 6;

  f32x4 acc[4][4];
  const f32x4 z4 = {0.f, 0.f, 0.f, 0.f};
  #pragma unroll
  for (int mi = 0; mi < 4; ++mi)
    #pragma unroll
    for (int ni = 0; ni < 4; ++ni) acc[mi][ni] = z4;

  for (int t = 0; t < 8; ++t) {
    const int kc = t * 32;
    float av[8];
    *(float4*)&av[0] = *(const float4*)&local_[(size_t)(gr0 + arow) * HID + kc + ag * 8];
    *(float4*)&av[4] = *(const float4*)&local_[(size_t)(gr0 + arow) * HID + kc + ag * 8 + 4];
    f16x8 wbh[4], wbl[4];
    #pragma unroll
    for (int gg = 0; gg < 4; ++gg) {
      wbh[gg] = *(const f16x8*)&W1hT[(size_t)tid * HID + kc + gg * 8];
      wbl[gg] = *(const f16x8*)&W1lT[(size_t)tid * HID + kc + gg * 8];
    }
    f16x8 ha, la;
    split8(av, ha, la);

    __syncthreads();
    *(f16x8*)&Ah[ag][arow][0] = ha;
    *(f16x8*)&Al[ag][arow][0] = la;
    #pragma unroll
    for (int gg = 0; gg < 4; ++gg) {
      *(f16x8*)&Bh[gg][tid][0] = wbh[gg];
      *(f16x8*)&Bl[gg][tid][0] = wbl[gg];
    }
    __syncthreads();

    f16x8 fah[4], fal[4], fbh[4], fbl[4];
    #pragma unroll
    for (int mi = 0; mi < 4; ++mi) {
      fah[mi] = *(const f16x8*)&Ah[kg][mi * 16 + lr][0];
      fal[mi] = *(const f16x8*)&Al[kg][mi * 16 + lr][0];
    }
    #pragma unroll
    for (int ni = 0; ni < 4; ++ni) {
      fbh[ni] = *(const f16x8*)&Bh[kg][w * 64 + ni * 16 + lr][0];
      fbl[ni] = *(const f16x8*)&Bl[kg][w * 64 + ni * 16 + lr][0];
    }
    #pragma unroll
    for (int mi = 0; mi < 4; ++mi)
      #pragma unroll
      for (int ni = 0; ni < 4; ++ni) {
        acc[mi][ni] = __builtin_amdgcn_mfma_f32_16x16x32_f16(fah[mi], fbh[ni], acc[mi][ni], 0, 0, 0);
        acc[mi][ni] = __builtin_amdgcn_mfma_f32_16x16x32_f16(fah[mi], fbl[ni], acc[mi][ni], 0, 0, 0);
        acc[mi][ni] = __builtin_amdgcn_mfma_f32_16x16x32_f16(fal[mi], fbh[ni], acc[mi][ni], 0, 0, 0);
      }
  }

  float w2v[4];
  #pragma unroll
  for (int ni = 0; ni < 4; ++ni) w2v[ni] = W2[w * 64 + ni * 16 + lr];
  #pragma unroll
  for (int mi = 0; mi < 4; ++mi) {
    #pragma unroll
    for (int i = 0; i < 4; ++i) {
      int row = gr0 + mi * 16 + kg * 4 + i;
      int bf = row / NTOK;
      float p1 = 0.f, p2 = 0.f;
      #pragma unroll
      for (int ni = 0; ni < 4; ++ni) {
        int col = w * 64 + ni * 16 + lr;
        float u = acc[mi][ni][i];
        p1 = fmaf(gelu32(u + c1[(size_t)bf * HID + col]), w2v[ni], p1);
        p2 = fmaf(gelu32(u + c2[(size_t)bf * HID + col]), w2v[ni], p2);
      }
      #pragma unroll
      for (int m = 1; m < 16; m <<= 1) { p1 += __shfl_xor(p1, m); p2 += __shfl_xor(p2, m); }
      if (lr == 0) {
        red1[mi * 16 + kg * 4 + i][w] = p1;
        red2[mi * 16 + kg * 4 + i][w] = p2;
      }
    }
  }
  __syncthreads();
  if (tid < 64) {
    float s1 = red1[tid][0] + red1[tid][1] + red1[tid][2] + red1[tid][3];
    float s2 = red2[tid][0] + red2[tid][1] + red2[tid][2] + red2[tid][3];
    scores[gr0 + tid] = tanhf(s1) + tanhf(s2);
  }
}

// ---------- K3: perturbed top-k, LDS counts, early-exit search ----------
// grid (96, SPB), 512 threads = 8 waves
__global__ __launch_bounds__(512) void k_topk(const float* __restrict__ scores,
                                              unsigned short* __restrict__ partial) {
  const int b = blockIdx.x, chunk = blockIdx.y;
  const int tid = threadIdx.x, lane = tid & 63, wv = tid >> 6;
  __shared__ float sc_s[NTOK];
  __shared__ int cnt_s[CNTSZ];
  if (tid < NTOK) sc_s[tid] = scores[b * NTOK + tid];
  for (int i = tid; i < CNTSZ; i += 512) cnt_s[i] = 0;
  __syncthreads();

  for (int s = chunk + SPB * wv; s < NS; s += SPB * 8) {
    const int sid = b * NS + s;
    unsigned key[4];
    #pragma unroll
    for (int c = 0; c < 4; ++c) {
      int j = c * 64 + lane;
      if (j < NTOK) {
        float n = noise_at((unsigned)sid * 196u + (unsigned)j);
        float p = fmaf(0.05f, n, sc_s[j]);
        unsigned ub = __float_as_uint(p);
        key[c] = (ub & 0x80000000u) ? ~ub : (ub | 0x80000000u);
      } else {
        key[c] = 0u;
      }
    }
    // binary search for 49th-largest; early exit when count == 49 exactly
    unsigned prefix = 0u;
    bool exact = false;
    for (int bit = 31; bit >= 0; --bit) {
      unsigned t = prefix | (1u << bit);
      int cn = 0;
      #pragma unroll
      for (int c = 0; c < 4; ++c) cn += __popcll(__ballot(key[c] >= t));
      if (cn >= TOPK) {
        prefix = t;
        if (cn == TOPK) { exact = true; break; }
      }
    }
    unsigned long long lt = (1ull << lane) - 1ull;
    bool sel[4];
    if (exact) {
      #pragma unroll
      for (int c = 0; c < 4; ++c) sel[c] = key[c] >= prefix;
    } else {
      unsigned long long mE[4];
      int cntG = 0;
      #pragma unroll
      for (int c = 0; c < 4; ++c) {
        cntG += __popcll(__ballot(key[c] > prefix));
        mE[c] = __ballot(key[c] == prefix);
      }
      int need = TOPK - cntG;
      #pragma unroll
      for (int c = 0; c < 4; ++c) {
        int er = 0;
        for (int cc = 0; cc < c; ++cc) er += __popcll(mE[cc]);
        er += __popcll(mE[c] & lt);
        sel[c] = (key[c] > prefix) || ((key[c] == prefix) && (er < need));
      }
    }
    unsigned long long mS[4];
    #pragma unroll
    for (int c = 0; c < 4; ++c) mS[c] = __ballot(sel[c]);
    int base = 0;
    #pragma unroll
    for (int c = 0; c < 4; ++c) {
      if (sel[c]) {
        int rank = base + __popcll(mS[c] & lt);
        int j = c * 64 + lane;
        atomicAdd(&cnt_s[rank * NTOK + j], 1);
      }
      base += __popcll(mS[c]);
    }
  }
  __syncthreads();
  unsigned short* dst = partial + ((size_t)b * SPB + chunk) * CNTSZ;
  for (int i = tid; i < CNTSZ; i += 512) dst[i] = (unsigned short)cnt_s[i];
}

// ---------- K4: out[b,k,:] = sum_l (sum_c partial)/500 * x[b,l,:] ----------
// 256 thr: deterministic ballot-compaction of nonzeros, split-half accumulation
__global__ __launch_bounds__(256) void k_out(const float* __restrict__ x,
                                             const unsigned short* __restrict__ partial,
                                             float* __restrict__ out) {
  int bk = blockIdx.x;
  int b = bk / TOPK, k = bk - b * TOPK;
  __shared__ float swv[NTOK];
  __shared__ int idxs[NTOK];
  __shared__ int wcnt[4];
  __shared__ int wbase[5];
  __shared__ float4 part2[128];
  const int tid = threadIdx.x, lane = tid & 63, wv = tid >> 6;

  int cval = 0;
  if (tid < NTOK) {
    #pragma unroll
    for (int cc = 0; cc < SPB; ++cc)
      cval += partial[((size_t)b * SPB + cc) * CNTSZ + k * NTOK + tid];
  }
  unsigned long long m = __ballot(cval != 0);
  if (lane == 0) wcnt[wv] = __popcll(m);
  __syncthreads();
  if (tid == 0) {
    int a = 0;
    #pragma unroll
    for (int i = 0; i < 4; ++i) { wbase[i] = a; a += wcnt[i]; }
    wbase[4] = a;
  }
  __syncthreads();
  if (cval != 0) {
    int pos = wbase[wv] + __popcll(m & ((1ull << lane) - 1ull));
    idxs[pos] = tid;
    swv[pos] = (float)cval * 0.002f;
  }
  __syncthreads();
  const int n = wbase[4];
  const int half = tid >> 7, d4 = tid & 127;
  const int i0 = half ? (n + 1) / 2 : 0;
  const int i1 = half ? n : (n + 1) / 2;
  float a0 = 0, a1 = 0, a2 = 0, a3 = 0;
  for (int i = i0; i < i1; ++i) {
    float w = swv[i];
    float4 xv = *(const float4*)(x + ((size_t)(b * NTOK + idxs[i])) * DIM + d4 * 4);
    a0 = fmaf(w, xv.x, a0); a1 = fmaf(w, xv.y, a1);
    a2 = fmaf(w, xv.z, a2); a3 = fmaf(w, xv.w, a3);
  }
  if (half == 1) part2[d4] = make_float4(a0, a1, a2, a3);
  __syncthreads();
  if (half == 0) {
    float4 p = part2[d4];
    float4 o = make_float4(a0 + p.x, a1 + p.y, a2 + p.z, a3 + p.w);
    *(float4*)(out + (size_t)bk * DIM + d4 * 4) = o;
  }
}

// ---------- launcher ----------
extern "C" void kernel_launch(void* const* d_in, const int* in_sizes, int n_in,
                              void* d_out, int out_size, void* d_ws, size_t ws_size,
                              hipStream_t stream) {
  const float* x       = (const float*)d_in[0];
  const float* gf      = (const float*)d_in[1];
  const float* gs      = (const float*)d_in[2];
  const float* ln_in_g = (const float*)d_in[3];
  const float* ln_in_b = (const float*)d_in[4];
  const float* W_in    = (const float*)d_in[5];
  const float* ln_gd_g = (const float*)d_in[6];
  const float* ln_gd_b = (const float*)d_in[7];
  const float* W_gd    = (const float*)d_in[8];
  const float* W_out1  = (const float*)d_in[9];
  const float* W_out2  = (const float*)d_in[10];
  float* out = (float*)d_out;

  // ws layout (~36.5 MB)
  char* p = (char*)d_ws;
  float* local_  = (float*)p;             p += (size_t)ROWS * HID * 4;          // 19.3 MB
  unsigned short* partial = (unsigned short*)p; p += (size_t)BP * SPB * CNTSZ * 2; // 14.75 MB
  float* stats   = (float*)p;             p += (size_t)ROWS * 2 * 4;
  float* c1      = (float*)p;             p += (size_t)BP * HID * 4;
  float* c2      = (float*)p;             p += (size_t)BP * HID * 4;
  float* scores  = (float*)p;             p += (size_t)ROWS * 4;
  _Float16* WhT  = (_Float16*)p;          p += (size_t)HID * DIM * 2;
  _Float16* WlT  = (_Float16*)p;          p += (size_t)HID * DIM * 2;
  _Float16* W1hT = (_Float16*)p;          p += (size_t)HID * HID * 2;
  _Float16* W1lT = (_Float16*)p;          p += (size_t)HID * HID * 2;

  k_pre<<<PRE_GLOB + PRE_PREP + PRE_STATS, 256, 0, stream>>>(
      gf, gs, ln_gd_g, ln_gd_b, W_gd, W_out1, c1,
      W_in, WhT, WlT, W1hT, W1lT, x, stats);
  k_g1<<<GBLK, 256, 0, stream>>>(x, stats, ln_in_g, ln_in_b, WhT, WlT, local_);
  k_g2<<<GBLK, 256, 0, stream>>>(local_, W1hT, W1lT, W_out2, c1, c2, scores);
  k_topk<<<dim3(BP, SPB), 512, 0, stream>>>(scores, partial);
  k_out<<<BP * TOPK, 256, 0, stream>>>(x, partial, out);
}